// Round 4
// baseline (159237.720 us; speedup 1.0000x reference)
//
#include <hip/hip_runtime.h>

#define GWG 256      // workgroups (1 per CU)
#define BTH 768      // threads per WG (12 waves)
#define WROW 2056    // padded LDS row pitch for Wih1 (bf16 elems)
#define LDSZ 120704

typedef float f4v __attribute__((ext_vector_type(4)));

// ---------- helpers ----------
__device__ __forceinline__ unsigned short b16(float f) {   // f32 -> bf16 (RNE)
  union { float f; unsigned int i; } z; z.f = f;
  unsigned int r = z.i + 0x7fffu + ((z.i >> 16) & 1u);
  return (unsigned short)(r >> 16);
}
__device__ __forceinline__ float bup(unsigned short u) {
  union { unsigned int i; float f; } z; z.i = ((unsigned int)u) << 16; return z.f;
}
__device__ __forceinline__ float blo(unsigned int p) {
  union { unsigned int i; float f; } z; z.i = p << 16; return z.f;
}
__device__ __forceinline__ float bhi(unsigned int p) {
  union { unsigned int i; float f; } z; z.i = p & 0xffff0000u; return z.f;
}
__device__ __forceinline__ float sigm(float x) { return 1.f / (1.f + expf(-x)); }

__device__ __forceinline__ void cohS(float* p, float v) {
  __hip_atomic_store(p, v, __ATOMIC_RELAXED, __HIP_MEMORY_SCOPE_AGENT);
}
__device__ __forceinline__ void cohSi(int* p, int v) {
  __hip_atomic_store(p, v, __ATOMIC_RELAXED, __HIP_MEMORY_SCOPE_AGENT);
}
__device__ __forceinline__ int cohLi(int* p) {
  return __hip_atomic_load(p, __ATOMIC_RELAXED, __HIP_MEMORY_SCOPE_AGENT);
}

// poll 8 line-padded counters (stride 16 ints = 64B) until all >= tgt
__device__ __forceinline__ void pollctr(int* c, int tgt) {
  if (threadIdx.x < 64) {
    int* q = c + (threadIdx.x & 7) * 16;
    while (cohLi(q) < tgt) __builtin_amdgcn_s_sleep(1);
  }
  __syncthreads();
}

// ---------- pre-kernels ----------
__global__ __launch_bounds__(256) void prep(const float* __restrict__ bih0, const float* __restrict__ bhh0,
                                            const float* __restrict__ bih1, const float* __restrict__ bhh1,
                                            float* __restrict__ b0, float* __restrict__ b1f,
                                            int* c1, int* cp, int* c2) {
  int i = blockIdx.x * 256 + threadIdx.x;
  if (i < 8192) { b0[i] = bih0[i] + bhh0[i]; b1f[i] = bih1[i] + bhh1[i]; }
  if (i < 8) { cohSi(&c1[i * 16], 0); cohSi(&cp[i * 16], 0); cohSi(&c2[i * 16], 0); }
}

__global__ __launch_bounds__(256) void transpose_wx(const float* __restrict__ Wih0, float* __restrict__ WxT) {
  int idx = blockIdx.x * 256 + threadIdx.x;          // 360*8192 total
  int r = idx & 8191, k = idx >> 13;
  WxT[(size_t)k * 8192 + r] = Wih0[(size_t)r * 424 + k];
}

// gates_x = inputVecs @ Wx^T + b0, stored bf16, only gate rows {i,g,o}
__global__ __launch_bounds__(256) void gemm_gx(const float* __restrict__ inV, const float* __restrict__ WxT,
                                               const float* __restrict__ b0, unsigned short* __restrict__ gxb) {
  __shared__ float lin[32 * 360];
  int t0 = blockIdx.x * 32;
  int by = blockIdx.y;                 // 0..23
  int ry = by >> 3;
  int gatey = ry + (ry ? 1 : 0);       // {0,2,3}
  int r = gatey * 2048 + (by & 7) * 256 + threadIdx.x;
  for (int i = threadIdx.x; i < 32 * 360; i += 256) lin[i] = inV[(size_t)t0 * 360 + i];
  __syncthreads();
  float b = b0[r];
  float acc[32];
#pragma unroll
  for (int tt = 0; tt < 32; ++tt) acc[tt] = b;
  for (int k = 0; k < 360; k += 4) {
    float w0 = WxT[(size_t)(k + 0) * 8192 + r];
    float w1 = WxT[(size_t)(k + 1) * 8192 + r];
    float w2 = WxT[(size_t)(k + 2) * 8192 + r];
    float w3 = WxT[(size_t)(k + 3) * 8192 + r];
#pragma unroll
    for (int tt = 0; tt < 32; ++tt) {
      float4 l = *reinterpret_cast<const float4*>(&lin[tt * 360 + k]);
      acc[tt] = fmaf(w0, l.x, fmaf(w1, l.y, fmaf(w2, l.z, fmaf(w3, l.w, acc[tt]))));
    }
  }
  for (int tt = 0; tt < 32; ++tt) gxb[(size_t)(t0 + tt) * 8192 + r] = b16(acc[tt]);
}

// ---------- persistent scan kernel ----------
struct KP {
  const float* Wih0; const float* Wih1; const float* Wlin;
  const float* Wmap; const float* bmap; const float* embed0; const float* b1f;
  const float* blin;
  const unsigned short* gxb;
  float* g_h0;       // 2048 f32, direct-pushed (sc1)
  float* xyp;        // 256 x 512 f32 partial-y slots
  float* g_ys;       // 8 x 512 f32 group sums
  float* out;
  int* c1; int* cp; int* c2;     // 8 counters each, stride 16 ints
};

__global__ __launch_bounds__(BTH) void lstm_seq(KP p) {
  extern __shared__ __align__(16) char smem[];
  unsigned short* lW1 = (unsigned short*)smem;                  // 24 x WROW  (Wih1 slice)
  unsigned short* lWe = (unsigned short*)(smem + 98688);        // 24 x 64    (We slice)
  unsigned short* lWc = (unsigned short*)(smem + 101760);       // 8 x 512    (Wlin cols 8w..8w+7)
  float* lH  = (float*)(smem + 109952);                         // 2048 (h0 gather)
  float* lY  = (float*)(smem + 118144);                         // 512  (partial-y scratch, then y)
  float* lE  = (float*)(smem + 120192);                         // 64   (embed)
  float* lR  = (float*)(smem + 120448);                         // 24+pad
  float* lH1 = (float*)(smem + 120576);                         // 8    (h1 local)
  float* lV  = (float*)(smem + 120608);                         // 8    (reduce staging)
  int*   lF  = (int*)  (smem + 120672);                         // leader flag

  const int w = blockIdx.x, tid = threadIdx.x;
  const int g = w >> 5;             // reduction group 0..7
  const int rl = tid >> 5;          // 0..23 gate-row
  const int l32 = tid & 31;
  const int g3 = rl >> 3;
  const int gate = g3 + (g3 ? 1 : 0);      // {0,2,3} = i,g,o
  const int gr = w * 8 + (rl & 7) + 2048 * gate;

  // ---- stage weights into LDS (once) ----
  for (int r2 = 0; r2 < 24; ++r2) {
    int gg = r2 >> 3; int grr = w * 8 + (r2 & 7) + 2048 * (gg + (gg ? 1 : 0));
    const float* src = p.Wih1 + (size_t)grr * 2048;
    for (int i = tid; i < 2048; i += BTH) lW1[r2 * WROW + i] = b16(src[i]);
  }
  for (int i = tid; i < 24 * 64; i += BTH) {
    int r2 = i >> 6, k = i & 63; int gg = r2 >> 3;
    int grr = w * 8 + (r2 & 7) + 2048 * (gg + (gg ? 1 : 0));
    lWe[r2 * 64 + k] = b16(p.Wih0[(size_t)grr * 424 + 360 + k]);
  }
  for (int i = tid; i < 8 * 512; i += BTH) {       // Wlin columns 8w..8w+7
    int j = i >> 9, r = i & 511;
    lWc[j * 512 + r] = b16(p.Wlin[(size_t)r * 2048 + w * 8 + j]);
  }
  unsigned int wm[32];               // Wmap fragment in VGPRs (pre-rotated)
  float bm = 0.f, rswp = 0.f;
  {
    int e = tid >> 3, l8 = tid & 7;
    if (tid < 512) {
      bm = p.bmap[e];
#pragma unroll
      for (int i = 0; i < 32; ++i) {
        int ii = (i + l8 * 4) & 31;
        int k = e * 512 + l8 * 64 + 2 * ii;
        wm[i] = ((unsigned int)b16(p.Wmap[k + 1]) << 16) | (unsigned int)b16(p.Wmap[k]);
        rswp += blo(wm[i]) + bhi(wm[i]);
      }
    } else {
#pragma unroll
      for (int i = 0; i < 32; ++i) wm[i] = 0u;
    }
  }
  const float b1r = p.b1f[gr];
  f4v blr4 = {};
  if (tid < 128) blr4 = *(const f4v*)&p.blin[tid * 4];
  if (tid < 64) lE[tid] = p.embed0[tid];
  unsigned short gxu = p.gxb[gr];                  // gx for t=0
  __syncthreads();

  for (int t = 0; t < 4096; ++t) {
    // prefetch gx(t+1) early; drained by the vmcnt below
    const size_t nidx = (size_t)(t < 4095 ? t + 1 : t) * 8192 + gr;
    const unsigned short gxu_n = p.gxb[nidx];
    // ---------- phase A: gates0 -> h0, push + arrive ----------
    {
      unsigned int uwp = *(const unsigned int*)&lWe[rl * 64 + l32 * 2];
      float2 ev = *(const float2*)&lE[l32 * 2];
      float a = fmaf(blo(uwp), ev.x, bhi(uwp) * ev.y);
      a += __shfl_xor(a, 1); a += __shfl_xor(a, 2); a += __shfl_xor(a, 4);
      a += __shfl_xor(a, 8); a += __shfl_xor(a, 16);
      if (l32 == 0) lR[rl] = a + bup(gxu);
    }
    __syncthreads();
    if (tid < 8) {
      float c = sigm(lR[tid]) * tanhf(lR[8 + tid]);
      float h = sigm(lR[16 + tid]) * tanhf(c);
      cohS(&p.g_h0[w * 8 + tid], h);
    }
    asm volatile("s_waitcnt vmcnt(0)" ::: "memory");      // wave0 h0 stores drained
    if (tid == 0) __hip_atomic_fetch_add(&p.c1[g * 16], 1, __ATOMIC_RELAXED, __HIP_MEMORY_SCOPE_AGENT);
    // ---------- hop1: gather h0 ----------
    pollctr(p.c1, 32 * (t + 1));
    {
      f4v hv4 = {};
      const float* hsrc = &p.g_h0[(tid & 511) * 4];
      if (tid < 512)
        asm volatile("global_load_dwordx4 %0, %1, off sc0 sc1" : "=v"(hv4) : "v"(hsrc) : "memory");
      asm volatile("s_waitcnt vmcnt(0)" ::: "memory");
      __builtin_amdgcn_sched_barrier(0);
      if (tid < 512) *(f4v*)&lH[tid * 4] = hv4;
    }
    __syncthreads();
    // ---------- phase B: h1 matvec + partial y ----------
    {
      float acc = 0.f;
      const unsigned short* wr = lW1 + rl * WROW;
#pragma unroll 4
      for (int mm = 0; mm < 16; ++mm) {
        int k = l32 * 4 + mm * 128;
        ushort4 uw = *(const ushort4*)&wr[k];
        float4 hv = *(const float4*)&lH[k];
        acc = fmaf(bup(uw.x), hv.x, acc);
        acc = fmaf(bup(uw.y), hv.y, acc);
        acc = fmaf(bup(uw.z), hv.z, acc);
        acc = fmaf(bup(uw.w), hv.w, acc);
      }
      acc += __shfl_xor(acc, 1); acc += __shfl_xor(acc, 2); acc += __shfl_xor(acc, 4);
      acc += __shfl_xor(acc, 8); acc += __shfl_xor(acc, 16);
      if (l32 == 0) lR[rl] = acc + b1r;
    }
    __syncthreads();
    if (tid < 8) {
      float c = sigm(lR[tid]) * tanhf(lR[8 + tid]);
      lH1[tid] = sigm(lR[16 + tid]) * tanhf(c);
    }
    __syncthreads();
    if (tid < 512) {                 // partial y (512) from 8 local h1
      float yp = 0.f;
#pragma unroll
      for (int j = 0; j < 8; ++j) yp = fmaf(bup(lWc[j * 512 + tid]), lH1[j], yp);
      lY[tid] = yp;
    }
    __syncthreads();
    if (tid < 128) {                 // push partial slot (plain coherent stores, no RMW)
      f4v v = *(const f4v*)&lY[tid * 4];
      float* dp = &p.xyp[(size_t)w * 512 + tid * 4];
      asm volatile("global_store_dwordx4 %0, %1, off sc0 sc1" :: "v"(dp), "v"(v) : "memory");
    }
    asm volatile("s_waitcnt vmcnt(0)" ::: "memory");
    __syncthreads();
    if (tid == 0) {
      int old = __hip_atomic_fetch_add(&p.cp[g * 16], 1, __ATOMIC_RELAXED, __HIP_MEMORY_SCOPE_AGENT);
      lF[0] = (old == 32 * (t + 1) - 1) ? 1 : 0;       // last arriver leads
    }
    __syncthreads();
    if (lF[0]) {
      // ---------- group leader: sum 32 partials, push group sum ----------
      if (tid < 128) {
        const float* base = p.xyp + ((size_t)(g * 32) * 512) + tid * 4;
        f4v acc = {};
#pragma unroll
        for (int b = 0; b < 2; ++b) {
          f4v vv[16];
#pragma unroll
          for (int s = 0; s < 16; ++s) {
            const float* ptr = base + (size_t)(b * 16 + s) * 512;
            asm volatile("global_load_dwordx4 %0, %1, off sc0 sc1" : "=v"(vv[s]) : "v"(ptr) : "memory");
          }
          asm volatile("s_waitcnt vmcnt(0)" ::: "memory");
          __builtin_amdgcn_sched_barrier(0);
#pragma unroll
          for (int s = 0; s < 16; ++s) acc += vv[s];
        }
        float* dp = &p.g_ys[g * 512 + tid * 4];
        asm volatile("global_store_dwordx4 %0, %1, off sc0 sc1" :: "v"(dp), "v"(acc) : "memory");
      }
      asm volatile("s_waitcnt vmcnt(0)" ::: "memory");
      __syncthreads();
      if (tid == 0) __hip_atomic_fetch_add(&p.c2[g * 16], 1, __ATOMIC_RELAXED, __HIP_MEMORY_SCOPE_AGENT);
    }
    // ---------- hop2: assemble y ----------
    pollctr(p.c2, t + 1);
    {
      f4v ys[8];
      if (tid < 128) {
#pragma unroll
        for (int gg = 0; gg < 8; ++gg) {
          const float* ptr = &p.g_ys[gg * 512 + tid * 4];
          asm volatile("global_load_dwordx4 %0, %1, off sc0 sc1" : "=v"(ys[gg]) : "v"(ptr) : "memory");
        }
      }
      asm volatile("s_waitcnt vmcnt(0)" ::: "memory");
      __builtin_amdgcn_sched_barrier(0);
      if (tid < 128) {
        f4v y4 = blr4;
#pragma unroll
        for (int gg = 0; gg < 8; ++gg) y4 += ys[gg];
        *(f4v*)&lY[tid * 4] = y4;
      }
    }
    __syncthreads();
    if (tid < 2) p.out[(size_t)t * 512 + w * 2 + tid] = lY[w * 2 + tid];
    // ---------- lse (no max: |y| < 2) + embed ----------
    float yv = 0.f, s = 0.f;
    if (tid < 512) {
      yv = lY[tid];
      s = expf(yv);
#pragma unroll
      for (int d = 1; d < 64; d <<= 1) s += __shfl_xor(s, d);
      if ((tid & 63) == 0) lV[tid >> 6] = s;
    }
    __syncthreads();
    float lse = logf(lV[0] + lV[1] + lV[2] + lV[3] + lV[4] + lV[5] + lV[6] + lV[7]);
    if (tid < 512) {
      int l8 = tid & 7, base = l8 * 64;
      float acc = 0.f;
#pragma unroll
      for (int i = 0; i < 32; ++i) {
        int k = base + 2 * ((i + l8 * 4) & 31);
        float2 yv2 = *(const float2*)&lY[k];
        acc = fmaf(blo(wm[i]), yv2.x, fmaf(bhi(wm[i]), yv2.y, acc));
      }
      acc -= lse * rswp;
      acc += __shfl_xor(acc, 1); acc += __shfl_xor(acc, 2); acc += __shfl_xor(acc, 4);
      if (l8 == 0) lE[tid >> 3] = acc + bm;
    }
    gxu = gxu_n;
    __syncthreads();
  }
}

// ---------- host ----------
extern "C" void kernel_launch(void* const* d_in, const int* in_sizes, int n_in,
                              void* d_out, int out_size, void* d_ws, size_t ws_size,
                              hipStream_t stream) {
  const float* inV  = (const float*)d_in[0];
  const float* Wih0 = (const float*)d_in[1];
  const float* bih0 = (const float*)d_in[2];
  const float* bhh0 = (const float*)d_in[3];
  const float* Wih1 = (const float*)d_in[4];
  const float* bih1 = (const float*)d_in[5];
  const float* bhh1 = (const float*)d_in[6];
  const float* Wlin = (const float*)d_in[7];
  const float* blin = (const float*)d_in[8];
  const float* Wmap = (const float*)d_in[9];
  const float* bmap = (const float*)d_in[10];
  const float* emb0 = (const float*)d_in[11];

  char* ws = (char*)d_ws;
  unsigned short* gxb = (unsigned short*)(ws);            // 67,108,864 B
  float* WxT   = (float*)(ws + 67108864);                 // 11,796,480 B
  float* b0    = (float*)(ws + 78905344);                 // 32 KB
  float* b1f   = (float*)(ws + 78938112);                 // 32 KB
  float* g_h0  = (float*)(ws + 78970880);                 // 8 KB
  float* xyp   = (float*)(ws + 78979072);                 // 256*512*4 = 512 KB
  float* g_ys  = (float*)(ws + 79503360);                 // 8*512*4 = 16 KB
  int*   c1    = (int*)  (ws + 79519744);                 // 8 x 64B
  int*   cp    = (int*)  (ws + 79520768);
  int*   c2    = (int*)  (ws + 79521792);
  float* out   = (float*)d_out;

  prep<<<32, 256, 0, stream>>>(bih0, bhh0, bih1, bhh1, b0, b1f, c1, cp, c2);
  transpose_wx<<<11520, 256, 0, stream>>>(Wih0, WxT);
  gemm_gx<<<dim3(128, 24), 256, 0, stream>>>(inV, WxT, b0, gxb);

  hipFuncSetAttribute(reinterpret_cast<const void*>(lstm_seq),
                      hipFuncAttributeMaxDynamicSharedMemorySize, LDSZ);
  KP p{Wih0, Wih1, Wlin, Wmap, bmap, emb0, b1f, blin, gxb, g_h0, xyp, g_ys, out, c1, cp, c2};
  void* args[] = { (void*)&p };
  hipError_t e = hipLaunchCooperativeKernel(reinterpret_cast<void*>(&lstm_seq),
                                            dim3(GWG), dim3(BTH), args, LDSZ, stream);
  if (e != hipSuccess) {
    lstm_seq<<<GWG, BTH, LDSZ, stream>>>(p);
  }
}

// Round 5
// 45327.100 us; speedup vs baseline: 3.5131x; 3.5131x over previous
//
#include <hip/hip_runtime.h>

#define GWG 256      // workgroups (1 per CU)
#define BTH 768      // threads per WG (12 waves)
#define WROW 2056    // padded LDS row pitch for Wih1 (bf16 elems)
#define LDSZ 141856

typedef float f4v __attribute__((ext_vector_type(4)));

// ---------- helpers ----------
__device__ __forceinline__ unsigned short b16(float f) {   // f32 -> bf16 (RNE)
  union { float f; unsigned int i; } z; z.f = f;
  unsigned int r = z.i + 0x7fffu + ((z.i >> 16) & 1u);
  return (unsigned short)(r >> 16);
}
__device__ __forceinline__ float bup(unsigned short u) {
  union { unsigned int i; float f; } z; z.i = ((unsigned int)u) << 16; return z.f;
}
__device__ __forceinline__ float sigm(float x) { return 1.f / (1.f + expf(-x)); }

// poll one 16B mailbox chunk until its embedded tag (lane 3) == want.
__device__ __forceinline__ f4v pollchunk(const float* ptr, int want) {
  f4v v;
  for (;;) {
    asm volatile("global_load_dwordx4 %0, %1, off sc0 sc1\n\ts_waitcnt vmcnt(0)"
                 : "=v"(v) : "v"(ptr) : "memory");
    if (__float_as_int(v[3]) == want) break;
    __builtin_amdgcn_s_sleep(1);
  }
  return v;
}
__device__ __forceinline__ void storechunk(float* ptr, f4v v) {
  asm volatile("global_store_dwordx4 %0, %1, off sc0 sc1" :: "v"(ptr), "v"(v) : "memory");
}

// ---------- pre-kernels ----------
__global__ __launch_bounds__(256) void prep(const float* __restrict__ bih0, const float* __restrict__ bhh0,
                                            const float* __restrict__ bih1, const float* __restrict__ bhh1,
                                            float* __restrict__ b0, float* __restrict__ b1f) {
  int i = blockIdx.x * 256 + threadIdx.x;
  if (i < 8192) { b0[i] = bih0[i] + bhh0[i]; b1f[i] = bih1[i] + bhh1[i]; }
}

__global__ __launch_bounds__(256) void transpose_wx(const float* __restrict__ Wih0, float* __restrict__ WxT) {
  int idx = blockIdx.x * 256 + threadIdx.x;          // 360*8192 total
  int r = idx & 8191, k = idx >> 13;
  WxT[(size_t)k * 8192 + r] = Wih0[(size_t)r * 424 + k];
}

// gates_x = inputVecs @ Wx^T + b0, stored bf16, only gate rows {i,g,o}
__global__ __launch_bounds__(256) void gemm_gx(const float* __restrict__ inV, const float* __restrict__ WxT,
                                               const float* __restrict__ b0, unsigned short* __restrict__ gxb) {
  __shared__ float lin[32 * 360];
  int t0 = blockIdx.x * 32;
  int by = blockIdx.y;                 // 0..23
  int ry = by >> 3;
  int gatey = ry + (ry ? 1 : 0);       // {0,2,3}
  int r = gatey * 2048 + (by & 7) * 256 + threadIdx.x;
  for (int i = threadIdx.x; i < 32 * 360; i += 256) lin[i] = inV[(size_t)t0 * 360 + i];
  __syncthreads();
  float b = b0[r];
  float acc[32];
#pragma unroll
  for (int tt = 0; tt < 32; ++tt) acc[tt] = b;
  for (int k = 0; k < 360; k += 4) {
    float w0 = WxT[(size_t)(k + 0) * 8192 + r];
    float w1 = WxT[(size_t)(k + 1) * 8192 + r];
    float w2 = WxT[(size_t)(k + 2) * 8192 + r];
    float w3 = WxT[(size_t)(k + 3) * 8192 + r];
#pragma unroll
    for (int tt = 0; tt < 32; ++tt) {
      float4 l = *reinterpret_cast<const float4*>(&lin[tt * 360 + k]);
      acc[tt] = fmaf(w0, l.x, fmaf(w1, l.y, fmaf(w2, l.z, fmaf(w3, l.w, acc[tt]))));
    }
  }
  for (int tt = 0; tt < 32; ++tt) gxb[(size_t)(t0 + tt) * 8192 + r] = b16(acc[tt]);
}

// Wcomb = We @ Wmap, compact igo rows [6144][512], bf16
__global__ __launch_bounds__(256) void wcomb_k(const float* __restrict__ Wih0, const float* __restrict__ Wmap,
                                               unsigned short* __restrict__ wcomb) {
  __shared__ float lwe[64];
  int cr = blockIdx.x;                               // compact row 0..6143
  int orig = cr + (cr >= 2048 ? 2048 : 0);           // gate {0,2,3}
  if (threadIdx.x < 64) lwe[threadIdx.x] = Wih0[(size_t)orig * 424 + 360 + threadIdx.x];
  __syncthreads();
  int c = threadIdx.x;
  float a0 = 0.f, a1 = 0.f;
  for (int e = 0; e < 64; ++e) {
    float w = lwe[e];
    a0 = fmaf(w, Wmap[e * 512 + c], a0);
    a1 = fmaf(w, Wmap[e * 512 + c + 256], a1);
  }
  wcomb[(size_t)cr * 512 + c] = b16(a0);
  wcomb[(size_t)cr * 512 + c + 256] = b16(a1);
}

// rs = rowsum(Wcomb_bf16); bcomb = We@bmap; g0c = We@embed0   (compact [6144])
__global__ __launch_bounds__(256) void rsk(const unsigned short* __restrict__ wcomb,
                                           const float* __restrict__ Wih0,
                                           const float* __restrict__ bmap, const float* __restrict__ emb0,
                                           float* __restrict__ rs, float* __restrict__ bcomb,
                                           float* __restrict__ g0c) {
  int cr = blockIdx.x * 256 + threadIdx.x;
  if (cr >= 6144) return;
  int orig = cr + (cr >= 2048 ? 2048 : 0);
  float s = 0.f;
  for (int k = 0; k < 512; ++k) s += bup(wcomb[(size_t)cr * 512 + k]);
  float bc = 0.f, g0 = 0.f;
  for (int e = 0; e < 64; ++e) {
    float w = Wih0[(size_t)orig * 424 + 360 + e];
    bc = fmaf(w, bmap[e], bc);
    g0 = fmaf(w, emb0[e], g0);
  }
  rs[cr] = s; bcomb[cr] = bc; g0c[cr] = g0;
}

// ---------- persistent scan kernel ----------
struct KP {
  const float* Wih1; const float* Wlin; const float* blin; const float* b1f;
  const unsigned short* gxb; const unsigned short* wcomb;
  const float* rs; const float* bcomb; const float* g0c;
  float* mb_h0; float* mb_h1; float* mb_y;     // tagged mailboxes
  float* out;
};

__global__ __launch_bounds__(BTH) void lstm_seq(KP p) {
  extern __shared__ __align__(16) char smem[];
  unsigned short* lW1  = (unsigned short*)smem;                 // 24 x WROW   (Wih1 slice)       98,688
  unsigned short* lWcb = (unsigned short*)(smem + 98688);       // 24 x 512    (Wcomb slice)      24,576
  unsigned short* lWl  = (unsigned short*)(smem + 123264);      // 2 x 2048    (Wlin rows)         8,192
  float* lH  = (float*)(smem + 131456);                         // 2048 (h0 / h1 gather)
  float* lY  = (float*)(smem + 139648);                         // 512
  float* lH1 = (float*)(smem + 141696);                         // 8
  float* lR  = (float*)(smem + 141728);                         // 24
  float* lV  = (float*)(smem + 141824);                         // 8

  const int w = blockIdx.x, tid = threadIdx.x;
  const int rl = tid >> 5;          // 0..23 gate-row
  const int l32 = tid & 31;
  const int g3 = rl >> 3;                   // 0,1,2  (i,g,o compact)
  const int gate = g3 + (g3 ? 1 : 0);       // {0,2,3} in original 4-gate layout
  const int gr  = w * 8 + (rl & 7) + 2048 * gate;      // row in gxb / b1f space
  const int crt = w * 8 + (rl & 7) + 2048 * g3;        // compact row (wcomb/rs/bcomb/g0c)

  // ---- stage weights into LDS (once) ----
  for (int r2 = 0; r2 < 24; ++r2) {
    int gg = r2 >> 3; int grr = w * 8 + (r2 & 7) + 2048 * (gg + (gg ? 1 : 0));
    const float* src = p.Wih1 + (size_t)grr * 2048;
    for (int i = tid; i < 2048; i += BTH) lW1[r2 * WROW + i] = b16(src[i]);
  }
  for (int i = tid; i < 24 * 512; i += BTH) {
    int r2 = i >> 9, k = i & 511;
    int crr = w * 8 + (r2 & 7) + 2048 * (r2 >> 3);
    lWcb[r2 * 512 + k] = p.wcomb[(size_t)crr * 512 + k];
  }
  for (int i = tid; i < 2 * 2048; i += BTH) {
    int q = i >> 11, k = i & 2047;
    lWl[i] = b16(p.Wlin[(size_t)(w * 2 + q) * 2048 + k]);
  }
  const float b1r = p.b1f[gr];
  const float rs_r = p.rs[crt], bc_r = p.bcomb[crt], g0_r = p.g0c[crt];
  const float bl0 = p.blin[w * 2], bl1 = p.blin[w * 2 + 1];
  unsigned short gxu = p.gxb[gr];                  // gx for t=0
  __syncthreads();

  const int mbq = tid >> 8;          // chunk 0..2
  const int mbm = tid & 255;         // mailbox index

  for (int t = 0; t < 4096; ++t) {
    // prefetch gx(t+1)
    const unsigned short gxu_n = p.gxb[(size_t)(t < 4095 ? t + 1 : t) * 8192 + gr];
    // ============ phase 1: consume y(t-1), lse, gates0 -> h0 ============
    if (t > 0) {
      if (tid < 256) {
        f4v c = pollchunk(p.mb_y + tid * 4, t);
        lY[2 * tid] = c[0]; lY[2 * tid + 1] = c[1];
      }
      __syncthreads();                                         // S1
      float yv = 0.f, s = 0.f;
      if (tid < 512) {
        yv = lY[tid];
        s = expf(yv);
#pragma unroll
        for (int d = 1; d < 64; d <<= 1) s += __shfl_xor(s, d);
        if ((tid & 63) == 0) lV[tid >> 6] = s;
      }
      __syncthreads();                                         // S2
      float lse = logf(lV[0] + lV[1] + lV[2] + lV[3] + lV[4] + lV[5] + lV[6] + lV[7]);
      float acc = 0.f;
#pragma unroll
      for (int j = 0; j < 16; ++j) {
        int k = l32 + 32 * j;
        acc = fmaf(bup(lWcb[rl * 512 + k]), lY[k], acc);
      }
      acc += __shfl_xor(acc, 1); acc += __shfl_xor(acc, 2); acc += __shfl_xor(acc, 4);
      acc += __shfl_xor(acc, 8); acc += __shfl_xor(acc, 16);
      if (l32 == 0) lR[rl] = bup(gxu) + acc - lse * rs_r + bc_r;
    } else {
      if (l32 == 0) lR[rl] = bup(gxu) + g0_r;
    }
    __syncthreads();                                           // S3
    if (tid < 8) {
      float c = sigm(lR[tid]) * tanhf(lR[8 + tid]);
      lH1[tid] = sigm(lR[16 + tid]) * tanhf(c);
    }
    __syncthreads();                                           // S4
    if (tid < 3) {                       // post h0 mailbox (3 tagged 16B chunks)
      f4v c;
#pragma unroll
      for (int i = 0; i < 3; ++i) { int idx = 3 * tid + i; c[i] = (idx < 8) ? lH1[idx] : 0.f; }
      c[3] = __int_as_float(t + 1);
      storechunk(p.mb_h0 + w * 16 + tid * 4, c);
    }
    // ============ phase 2: gather h0, h1 matvec ============
    {
      f4v c = pollchunk(p.mb_h0 + mbm * 16 + mbq * 4, t + 1);
#pragma unroll
      for (int i = 0; i < 3; ++i) { int idx = 3 * mbq + i; if (idx < 8) lH[mbm * 8 + idx] = c[i]; }
    }
    __syncthreads();                                           // S5
    {
      float acc = 0.f;
      const unsigned short* wr = lW1 + rl * WROW;
#pragma unroll 4
      for (int mm = 0; mm < 16; ++mm) {
        int k = l32 * 4 + mm * 128;
        ushort4 uw = *(const ushort4*)&wr[k];
        float4 hv = *(const float4*)&lH[k];
        acc = fmaf(bup(uw.x), hv.x, acc);
        acc = fmaf(bup(uw.y), hv.y, acc);
        acc = fmaf(bup(uw.z), hv.z, acc);
        acc = fmaf(bup(uw.w), hv.w, acc);
      }
      acc += __shfl_xor(acc, 1); acc += __shfl_xor(acc, 2); acc += __shfl_xor(acc, 4);
      acc += __shfl_xor(acc, 8); acc += __shfl_xor(acc, 16);
      if (l32 == 0) lR[rl] = acc + b1r;
    }
    __syncthreads();                                           // S6
    if (tid < 8) {
      float c = sigm(lR[tid]) * tanhf(lR[8 + tid]);
      lH1[tid] = sigm(lR[16 + tid]) * tanhf(c);
    }
    __syncthreads();                                           // S7
    if (tid < 3) {                       // post h1 mailbox
      f4v c;
#pragma unroll
      for (int i = 0; i < 3; ++i) { int idx = 3 * tid + i; c[i] = (idx < 8) ? lH1[idx] : 0.f; }
      c[3] = __int_as_float(t + 1);
      storechunk(p.mb_h1 + w * 16 + tid * 4, c);
    }
    // ============ phase 3: gather h1, y rows, post y ============
    {
      f4v c = pollchunk(p.mb_h1 + mbm * 16 + mbq * 4, t + 1);
#pragma unroll
      for (int i = 0; i < 3; ++i) { int idx = 3 * mbq + i; if (idx < 8) lH[mbm * 8 + idx] = c[i]; }
    }
    __syncthreads();                                           // S8
    if (tid < 512) {
      int q = tid >> 8, l = tid & 255;
      int k = l * 8;
      ushort4 uw0 = *(const ushort4*)&lWl[q * 2048 + k];
      ushort4 uw1 = *(const ushort4*)&lWl[q * 2048 + k + 4];
      float4 h0v = *(const float4*)&lH[k];
      float4 h1v = *(const float4*)&lH[k + 4];
      float a = fmaf(bup(uw0.x), h0v.x, fmaf(bup(uw0.y), h0v.y,
                fmaf(bup(uw0.z), h0v.z, fmaf(bup(uw0.w), h0v.w, 0.f))));
      a = fmaf(bup(uw1.x), h1v.x, fmaf(bup(uw1.y), h1v.y,
            fmaf(bup(uw1.z), h1v.z, fmaf(bup(uw1.w), h1v.w, a))));
#pragma unroll
      for (int d = 1; d < 64; d <<= 1) a += __shfl_xor(a, d);
      if ((tid & 63) == 0) lV[tid >> 6] = a;
    }
    __syncthreads();                                           // S9
    if (tid == 0) {
      float y0 = lV[0] + lV[1] + lV[2] + lV[3] + bl0;
      float y1 = lV[4] + lV[5] + lV[6] + lV[7] + bl1;
      p.out[(size_t)t * 512 + w * 2]     = y0;
      p.out[(size_t)t * 512 + w * 2 + 1] = y1;
      f4v c; c[0] = y0; c[1] = y1; c[2] = 0.f; c[3] = __int_as_float(t + 1);
      storechunk(p.mb_y + w * 4, c);
    }
    gxu = gxu_n;
  }
}

// ---------- host ----------
extern "C" void kernel_launch(void* const* d_in, const int* in_sizes, int n_in,
                              void* d_out, int out_size, void* d_ws, size_t ws_size,
                              hipStream_t stream) {
  const float* inV  = (const float*)d_in[0];
  const float* Wih0 = (const float*)d_in[1];
  const float* bih0 = (const float*)d_in[2];
  const float* bhh0 = (const float*)d_in[3];
  const float* Wih1 = (const float*)d_in[4];
  const float* bih1 = (const float*)d_in[5];
  const float* bhh1 = (const float*)d_in[6];
  const float* Wlin = (const float*)d_in[7];
  const float* blin = (const float*)d_in[8];
  const float* Wmap = (const float*)d_in[9];
  const float* bmap = (const float*)d_in[10];
  const float* emb0 = (const float*)d_in[11];

  char* ws = (char*)d_ws;
  unsigned short* gxb   = (unsigned short*)(ws);          // 67,108,864 B
  float*          WxT   = (float*)(ws + 67108864);        // 11,796,480 B (dead after gemm_gx)
  unsigned short* wcomb = (unsigned short*)(ws + 67108864);  // 6,291,456 B (aliases WxT, used after)
  float* b0    = (float*)(ws + 78905344);                 // 32 KB
  float* b1f   = (float*)(ws + 78938112);                 // 32 KB
  float* mb_h0 = (float*)(ws + 78970880);                 // 16 KB (256 x 64B tagged)
  float* mb_h1 = (float*)(ws + 78987264);                 // 16 KB
  float* mb_y  = (float*)(ws + 79003648);                 //  4 KB (256 x 16B tagged)
  float* rs    = (float*)(ws + 79007744);                 // 24 KB
  float* bcomb = (float*)(ws + 79032320);                 // 24 KB
  float* g0c   = (float*)(ws + 79056896);                 // 24 KB
  float* out   = (float*)d_out;

  prep<<<32, 256, 0, stream>>>(bih0, bhh0, bih1, bhh1, b0, b1f);
  transpose_wx<<<11520, 256, 0, stream>>>(Wih0, WxT);
  gemm_gx<<<dim3(128, 24), 256, 0, stream>>>(inV, WxT, b0, gxb);
  wcomb_k<<<6144, 256, 0, stream>>>(Wih0, Wmap, wcomb);        // overwrites WxT region (now dead)
  rsk<<<24, 256, 0, stream>>>(wcomb, Wih0, bmap, emb0, rs, bcomb, g0c);

  hipFuncSetAttribute(reinterpret_cast<const void*>(lstm_seq),
                      hipFuncAttributeMaxDynamicSharedMemorySize, LDSZ);
  KP p{Wih1, Wlin, blin, b1f, gxb, wcomb, rs, bcomb, g0c, mb_h0, mb_h1, mb_y, out};
  void* args[] = { (void*)&p };
  hipError_t e = hipLaunchCooperativeKernel(reinterpret_cast<void*>(&lstm_seq),
                                            dim3(GWG), dim3(BTH), args, LDSZ, stream);
  if (e != hipSuccess) {
    lstm_seq<<<GWG, BTH, LDSZ, stream>>>(p);
  }
}